// Round 1
// baseline (1903.586 us; speedup 1.0000x reference)
//
#include <hip/hip_runtime.h>

#define T_TOK 8192
#define HDIM 2048
#define IDIM 1408
#define NEXP 8

#define BM 128
#define BN 128
#define BK 64
#define LDK 72  // BK + 8 pad: keeps 16B alignment, 4-bank rotation/row -> ~2-way (free)

typedef short s16x8 __attribute__((ext_vector_type(8)));
typedef float f32x4 __attribute__((ext_vector_type(4)));
typedef unsigned short ushort_t;

__device__ __forceinline__ ushort_t f2bf(float f) {
  unsigned int u = __float_as_uint(f);
  unsigned int r = (u + 0x7fffu + ((u >> 16) & 1u)) >> 16;  // RNE
  return (ushort_t)r;
}

// ---------- Kernel A: RMSNorm + fp32 router + top2 scatter ----------
__global__ __launch_bounds__(256) void k_rms_router(
    const float* __restrict__ x, const float* __restrict__ rmsw,
    const float* __restrict__ rw, ushort_t* __restrict__ xnorm,
    float* __restrict__ logits_out, int* __restrict__ counts,
    int* __restrict__ tokens, float* __restrict__ pairw)
{
  const int t = blockIdx.x;
  const int tid = threadIdx.x;
  const float* xr = x + (size_t)t * HDIM + tid * 8;
  float4 a = *(const float4*)xr;
  float4 b = *(const float4*)(xr + 4);
  float xi[8] = {a.x, a.y, a.z, a.w, b.x, b.y, b.z, b.w};
  float ss = 0.f;
  #pragma unroll
  for (int i = 0; i < 8; i++) ss += xi[i] * xi[i];
  #pragma unroll
  for (int o = 32; o > 0; o >>= 1) ss += __shfl_down(ss, o, 64);
  __shared__ float s_red[4];
  if ((tid & 63) == 0) s_red[tid >> 6] = ss;
  __syncthreads();
  float tot = s_red[0] + s_red[1] + s_red[2] + s_red[3];
  float rstd = rsqrtf(tot * (1.0f / HDIM) + 1e-6f);

  const float* wwp = rmsw + tid * 8;
  #pragma unroll
  for (int i = 0; i < 8; i++) xi[i] = xi[i] * rstd * wwp[i];

  union { ushort_t us[8]; uint4 v; } pk;
  #pragma unroll
  for (int i = 0; i < 8; i++) pk.us[i] = f2bf(xi[i]);
  *(uint4*)(xnorm + (size_t)t * HDIM + tid * 8) = pk.v;

  // router logits in fp32 (selection must match reference)
  float lg[8];
  #pragma unroll
  for (int e = 0; e < 8; e++) {
    const float4* wr = (const float4*)(rw + e * HDIM + tid * 8);
    float4 w0 = wr[0], w1 = wr[1];
    lg[e] = xi[0]*w0.x + xi[1]*w0.y + xi[2]*w0.z + xi[3]*w0.w
          + xi[4]*w1.x + xi[5]*w1.y + xi[6]*w1.z + xi[7]*w1.w;
  }
  #pragma unroll
  for (int e = 0; e < 8; e++) {
    #pragma unroll
    for (int o = 32; o > 0; o >>= 1) lg[e] += __shfl_down(lg[e], o, 64);
  }
  __shared__ float s_lg[4][8];
  if ((tid & 63) == 0) {
    #pragma unroll
    for (int e = 0; e < 8; e++) s_lg[tid >> 6][e] = lg[e];
  }
  __syncthreads();
  __shared__ float s_fin[8];
  if (tid < 8) {
    float l = s_lg[0][tid] + s_lg[1][tid] + s_lg[2][tid] + s_lg[3][tid];
    logits_out[(size_t)t * NEXP + tid] = l;
    s_fin[tid] = l;
  }
  __syncthreads();
  if (tid == 0) {
    int i0 = 0;
    #pragma unroll
    for (int e = 1; e < 8; e++) if (s_fin[e] > s_fin[i0]) i0 = e;
    int i1 = (i0 == 0) ? 1 : 0;
    #pragma unroll
    for (int e = 0; e < 8; e++) if (e != i0 && s_fin[e] > s_fin[i1]) i1 = e;
    // normalized top-2 weights: softmax denom cancels
    float p1 = __expf(s_fin[i1] - s_fin[i0]);
    float inv = 1.0f / (1.0f + p1);
    float w0 = inv, w1 = p1 * inv;
    int s0 = atomicAdd(&counts[i0], 1);
    tokens[i0 * T_TOK + s0] = t; pairw[i0 * T_TOK + s0] = w0;
    int s1 = atomicAdd(&counts[i1], 1);
    tokens[i1 * T_TOK + s1] = t; pairw[i1 * T_TOK + s1] = w1;
  }
}

// ---------- Kernel A2: 8-wide exclusive scan ----------
__global__ void k_scan(const int* __restrict__ counts, int* __restrict__ basep) {
  if (threadIdx.x == 0) {
    int s = 0;
    for (int e = 0; e < NEXP; e++) { basep[e] = s; s += counts[e]; }
  }
}

// ---------- Kernel B: gathered gate+up GEMM + silu -> h (bf16) ----------
__global__ __launch_bounds__(256, 2) void k_gateup(
    const ushort_t* __restrict__ xnorm, const float* __restrict__ wg,
    const float* __restrict__ wu, const int* __restrict__ tokens,
    const int* __restrict__ counts, const int* __restrict__ basep,
    ushort_t* __restrict__ hbuf)
{
  const int e = blockIdx.z;
  const int cnt = counts[e];
  const int m0 = blockIdx.x * BM;
  if (m0 >= cnt) return;
  const int n0 = blockIdx.y * BN;
  const int tid = threadIdx.x;

  __shared__ ushort_t As[BM * LDK];
  __shared__ ushort_t Bgs[BN * LDK];
  __shared__ ushort_t Bus[BN * LDK];

  const int r = tid >> 1;
  const int col0 = (tid & 1) * 32;
  const int slot = (m0 + r < cnt) ? (m0 + r) : (cnt - 1);
  const int tok = tokens[e * T_TOK + slot];
  const ushort_t* asrc = xnorm + (size_t)tok * HDIM + col0;
  const float* gsrc = wg + ((size_t)e * IDIM + n0 + r) * HDIM + col0;
  const float* usrc = wu + ((size_t)e * IDIM + n0 + r) * HDIM + col0;

  const int lane = tid & 63;
  const int wid = tid >> 6;
  const int wm = (wid & 1) * 64;
  const int wn = (wid >> 1) * 64;
  const int fr = lane & 15;
  const int fq = lane >> 4;

  f32x4 accg[4][4] = {};
  f32x4 accu[4][4] = {};

  for (int k0 = 0; k0 < HDIM; k0 += BK) {
    #pragma unroll
    for (int i = 0; i < 4; i++) {
      uint4 v = *(const uint4*)(asrc + k0 + i * 8);
      *(uint4*)(&As[r * LDK + col0 + i * 8]) = v;
    }
    #pragma unroll
    for (int i = 0; i < 4; i++) {
      float4 f0 = *(const float4*)(gsrc + k0 + i * 8);
      float4 f1 = *(const float4*)(gsrc + k0 + i * 8 + 4);
      union { ushort_t us[8]; uint4 v; } p;
      p.us[0]=f2bf(f0.x); p.us[1]=f2bf(f0.y); p.us[2]=f2bf(f0.z); p.us[3]=f2bf(f0.w);
      p.us[4]=f2bf(f1.x); p.us[5]=f2bf(f1.y); p.us[6]=f2bf(f1.z); p.us[7]=f2bf(f1.w);
      *(uint4*)(&Bgs[r * LDK + col0 + i * 8]) = p.v;
    }
    #pragma unroll
    for (int i = 0; i < 4; i++) {
      float4 f0 = *(const float4*)(usrc + k0 + i * 8);
      float4 f1 = *(const float4*)(usrc + k0 + i * 8 + 4);
      union { ushort_t us[8]; uint4 v; } p;
      p.us[0]=f2bf(f0.x); p.us[1]=f2bf(f0.y); p.us[2]=f2bf(f0.z); p.us[3]=f2bf(f0.w);
      p.us[4]=f2bf(f1.x); p.us[5]=f2bf(f1.y); p.us[6]=f2bf(f1.z); p.us[7]=f2bf(f1.w);
      *(uint4*)(&Bus[r * LDK + col0 + i * 8]) = p.v;
    }
    __syncthreads();
    #pragma unroll
    for (int kk = 0; kk < BK; kk += 32) {
      s16x8 af[4], bg[4], bu[4];
      #pragma unroll
      for (int mi = 0; mi < 4; mi++)
        af[mi] = *(const s16x8*)(&As[(wm + mi * 16 + fr) * LDK + kk + fq * 8]);
      #pragma unroll
      for (int ni = 0; ni < 4; ni++) {
        bg[ni] = *(const s16x8*)(&Bgs[(wn + ni * 16 + fr) * LDK + kk + fq * 8]);
        bu[ni] = *(const s16x8*)(&Bus[(wn + ni * 16 + fr) * LDK + kk + fq * 8]);
      }
      #pragma unroll
      for (int mi = 0; mi < 4; mi++) {
        #pragma unroll
        for (int ni = 0; ni < 4; ni++) {
          accg[mi][ni] = __builtin_amdgcn_mfma_f32_16x16x32_bf16(af[mi], bg[ni], accg[mi][ni], 0, 0, 0);
          accu[mi][ni] = __builtin_amdgcn_mfma_f32_16x16x32_bf16(af[mi], bu[ni], accu[mi][ni], 0, 0, 0);
        }
      }
    }
    __syncthreads();
  }

  const int hb = basep[e];
  #pragma unroll
  for (int mi = 0; mi < 4; mi++) {
    #pragma unroll
    for (int reg = 0; reg < 4; reg++) {
      const int rl = wm + mi * 16 + fq * 4 + reg;  // C/D: row = quad*4+reg
      if (m0 + rl < cnt) {
        ushort_t* hrow = hbuf + (size_t)(hb + m0 + rl) * IDIM + n0;
        #pragma unroll
        for (int ni = 0; ni < 4; ni++) {
          float g = accg[mi][ni][reg];
          float u = accu[mi][ni][reg];
          float hv = (g / (1.0f + __expf(-g))) * u;  // silu(g)*u
          hrow[wn + ni * 16 + fr] = f2bf(hv);        // C/D: col = lane&15
        }
      }
    }
  }
}

// ---------- Kernel C: down GEMM + weighted atomic combine ----------
__global__ __launch_bounds__(256, 2) void k_down(
    const ushort_t* __restrict__ hbuf, const float* __restrict__ wd,
    const int* __restrict__ tokens, const float* __restrict__ pairw,
    const int* __restrict__ counts, const int* __restrict__ basep,
    float* __restrict__ out)
{
  const int e = blockIdx.z;
  const int cnt = counts[e];
  const int m0 = blockIdx.x * BM;
  if (m0 >= cnt) return;
  const int n0 = blockIdx.y * BN;  // over HDIM
  const int tid = threadIdx.x;
  const int hb = basep[e];

  __shared__ ushort_t As[BM * LDK];
  __shared__ ushort_t Bs[BN * LDK];

  const int r = tid >> 1;
  const int col0 = (tid & 1) * 32;
  const int slot = (m0 + r < cnt) ? (m0 + r) : (cnt - 1);
  const ushort_t* asrc = hbuf + (size_t)(hb + slot) * IDIM + col0;
  const float* bsrc = wd + ((size_t)e * HDIM + n0 + r) * IDIM + col0;

  const int lane = tid & 63;
  const int wid = tid >> 6;
  const int wm = (wid & 1) * 64;
  const int wn = (wid >> 1) * 64;
  const int fr = lane & 15;
  const int fq = lane >> 4;

  f32x4 acc[4][4] = {};

  for (int k0 = 0; k0 < IDIM; k0 += BK) {  // 1408/64 = 22 iters
    #pragma unroll
    for (int i = 0; i < 4; i++) {
      uint4 v = *(const uint4*)(asrc + k0 + i * 8);
      *(uint4*)(&As[r * LDK + col0 + i * 8]) = v;
    }
    #pragma unroll
    for (int i = 0; i < 4; i++) {
      float4 f0 = *(const float4*)(bsrc + k0 + i * 8);
      float4 f1 = *(const float4*)(bsrc + k0 + i * 8 + 4);
      union { ushort_t us[8]; uint4 v; } p;
      p.us[0]=f2bf(f0.x); p.us[1]=f2bf(f0.y); p.us[2]=f2bf(f0.z); p.us[3]=f2bf(f0.w);
      p.us[4]=f2bf(f1.x); p.us[5]=f2bf(f1.y); p.us[6]=f2bf(f1.z); p.us[7]=f2bf(f1.w);
      *(uint4*)(&Bs[r * LDK + col0 + i * 8]) = p.v;
    }
    __syncthreads();
    #pragma unroll
    for (int kk = 0; kk < BK; kk += 32) {
      s16x8 af[4], bf[4];
      #pragma unroll
      for (int mi = 0; mi < 4; mi++)
        af[mi] = *(const s16x8*)(&As[(wm + mi * 16 + fr) * LDK + kk + fq * 8]);
      #pragma unroll
      for (int ni = 0; ni < 4; ni++)
        bf[ni] = *(const s16x8*)(&Bs[(wn + ni * 16 + fr) * LDK + kk + fq * 8]);
      #pragma unroll
      for (int mi = 0; mi < 4; mi++) {
        #pragma unroll
        for (int ni = 0; ni < 4; ni++)
          acc[mi][ni] = __builtin_amdgcn_mfma_f32_16x16x32_bf16(af[mi], bf[ni], acc[mi][ni], 0, 0, 0);
      }
    }
    __syncthreads();
  }

  #pragma unroll
  for (int mi = 0; mi < 4; mi++) {
    #pragma unroll
    for (int reg = 0; reg < 4; reg++) {
      const int rl = wm + mi * 16 + fq * 4 + reg;
      if (m0 + rl < cnt) {
        const int tok = tokens[e * T_TOK + m0 + rl];
        const float w = pairw[e * T_TOK + m0 + rl];
        float* orow = out + (size_t)tok * HDIM + n0;
        #pragma unroll
        for (int ni = 0; ni < 4; ni++)
          atomicAdd(&orow[wn + ni * 16 + fr], w * acc[mi][ni][reg]);
      }
    }
  }
}

extern "C" void kernel_launch(void* const* d_in, const int* in_sizes, int n_in,
                              void* d_out, int out_size, void* d_ws, size_t ws_size,
                              hipStream_t stream)
{
  (void)in_sizes; (void)n_in; (void)ws_size;
  const float* x    = (const float*)d_in[0];
  const float* rmsw = (const float*)d_in[1];
  const float* rw   = (const float*)d_in[2];
  const float* wg   = (const float*)d_in[3];
  const float* wu   = (const float*)d_in[4];
  const float* wd   = (const float*)d_in[5];
  float* out = (float*)d_out;
  float* logits_out = out + (size_t)T_TOK * HDIM;

  // ws layout (~80.2 MB total)
  char* ws = (char*)d_ws;
  int* counts     = (int*)ws;                                   // 32 B
  int* basep      = (int*)(ws + 256);                           // 32 B
  ushort_t* xnorm = (ushort_t*)(ws + 512);                      // 33,554,432 B
  size_t off = 512 + (size_t)T_TOK * HDIM * 2;
  int* tokens     = (int*)(ws + off);                           // 262,144 B
  float* pairw    = (float*)(ws + off + (size_t)NEXP * T_TOK * 4);   // 262,144 B
  ushort_t* hbuf  = (ushort_t*)(ws + off + (size_t)NEXP * T_TOK * 8); // 46,137,344 B

  hipMemsetAsync(d_out, 0, (size_t)out_size * sizeof(float), stream);
  hipMemsetAsync(d_ws, 0, 512, stream);  // zero counts

  k_rms_router<<<T_TOK, 256, 0, stream>>>(x, rmsw, rw, xnorm, logits_out,
                                          counts, tokens, pairw);
  k_scan<<<1, 64, 0, stream>>>(counts, basep);
  k_gateup<<<dim3(T_TOK / BM, IDIM / BN, NEXP), 256, 0, stream>>>(
      xnorm, wg, wu, tokens, counts, basep, hbuf);
  k_down<<<dim3(T_TOK / BM, HDIM / BN, NEXP), 256, 0, stream>>>(
      hbuf, wd, tokens, pairw, counts, basep, out);
}

// Round 2
// 1193.067 us; speedup vs baseline: 1.5955x; 1.5955x over previous
//
#include <hip/hip_runtime.h>

#define T_TOK 8192
#define HDIM 2048
#define IDIM 1408
#define NEXP 8

#define BM 128
#define BN 128
#define BK 64
#define LDK 72  // fallback (fp32-staging) path only

typedef short s16x8 __attribute__((ext_vector_type(8)));
typedef float f32x4 __attribute__((ext_vector_type(4)));
typedef unsigned short ushort_t;

__device__ __forceinline__ ushort_t f2bf(float f) {
  unsigned int u = __float_as_uint(f);
  unsigned int r = (u + 0x7fffu + ((u >> 16) & 1u)) >> 16;  // RNE
  return (ushort_t)r;
}

// async global->LDS, 16B per lane; lds base must be wave-uniform, HW adds lane*16
__device__ __forceinline__ void gll16(const void* g, void* lds) {
  __builtin_amdgcn_global_load_lds(
      (const __attribute__((address_space(1))) unsigned int*)g,
      (__attribute__((address_space(3))) unsigned int*)lds, 16, 0, 0);
}

// ---------- fp32 -> bf16 bulk cast (8 elems/thread) ----------
__global__ __launch_bounds__(256) void k_cast(const float* __restrict__ src,
                                              ushort_t* __restrict__ dst, int n8) {
  int i = blockIdx.x * blockDim.x + threadIdx.x;
  if (i < n8) {
    float4 f0 = ((const float4*)src)[(size_t)i * 2];
    float4 f1 = ((const float4*)src)[(size_t)i * 2 + 1];
    union { ushort_t us[8]; uint4 v; } p;
    p.us[0]=f2bf(f0.x); p.us[1]=f2bf(f0.y); p.us[2]=f2bf(f0.z); p.us[3]=f2bf(f0.w);
    p.us[4]=f2bf(f1.x); p.us[5]=f2bf(f1.y); p.us[6]=f2bf(f1.z); p.us[7]=f2bf(f1.w);
    ((uint4*)dst)[i] = p.v;
  }
}

// ---------- Kernel A: RMSNorm + fp32 router + top2 scatter ----------
__global__ __launch_bounds__(256) void k_rms_router(
    const float* __restrict__ x, const float* __restrict__ rmsw,
    const float* __restrict__ rw, ushort_t* __restrict__ xnorm,
    float* __restrict__ logits_out, int* __restrict__ counts,
    int* __restrict__ tokens, float* __restrict__ pairw)
{
  const int t = blockIdx.x;
  const int tid = threadIdx.x;
  const float* xr = x + (size_t)t * HDIM + tid * 8;
  float4 a = *(const float4*)xr;
  float4 b = *(const float4*)(xr + 4);
  float xi[8] = {a.x, a.y, a.z, a.w, b.x, b.y, b.z, b.w};
  float ss = 0.f;
  #pragma unroll
  for (int i = 0; i < 8; i++) ss += xi[i] * xi[i];
  #pragma unroll
  for (int o = 32; o > 0; o >>= 1) ss += __shfl_down(ss, o, 64);
  __shared__ float s_red[4];
  if ((tid & 63) == 0) s_red[tid >> 6] = ss;
  __syncthreads();
  float tot = s_red[0] + s_red[1] + s_red[2] + s_red[3];
  float rstd = rsqrtf(tot * (1.0f / HDIM) + 1e-6f);

  const float* wwp = rmsw + tid * 8;
  #pragma unroll
  for (int i = 0; i < 8; i++) xi[i] = xi[i] * rstd * wwp[i];

  union { ushort_t us[8]; uint4 v; } pk;
  #pragma unroll
  for (int i = 0; i < 8; i++) pk.us[i] = f2bf(xi[i]);
  *(uint4*)(xnorm + (size_t)t * HDIM + tid * 8) = pk.v;

  float lg[8];
  #pragma unroll
  for (int e = 0; e < 8; e++) {
    const float4* wr = (const float4*)(rw + e * HDIM + tid * 8);
    float4 w0 = wr[0], w1 = wr[1];
    lg[e] = xi[0]*w0.x + xi[1]*w0.y + xi[2]*w0.z + xi[3]*w0.w
          + xi[4]*w1.x + xi[5]*w1.y + xi[6]*w1.z + xi[7]*w1.w;
  }
  #pragma unroll
  for (int e = 0; e < 8; e++) {
    #pragma unroll
    for (int o = 32; o > 0; o >>= 1) lg[e] += __shfl_down(lg[e], o, 64);
  }
  __shared__ float s_lg[4][8];
  if ((tid & 63) == 0) {
    #pragma unroll
    for (int e = 0; e < 8; e++) s_lg[tid >> 6][e] = lg[e];
  }
  __syncthreads();
  __shared__ float s_fin[8];
  if (tid < 8) {
    float l = s_lg[0][tid] + s_lg[1][tid] + s_lg[2][tid] + s_lg[3][tid];
    logits_out[(size_t)t * NEXP + tid] = l;
    s_fin[tid] = l;
  }
  __syncthreads();
  if (tid == 0) {
    int i0 = 0;
    #pragma unroll
    for (int e = 1; e < 8; e++) if (s_fin[e] > s_fin[i0]) i0 = e;
    int i1 = (i0 == 0) ? 1 : 0;
    #pragma unroll
    for (int e = 0; e < 8; e++) if (e != i0 && s_fin[e] > s_fin[i1]) i1 = e;
    float p1 = __expf(s_fin[i1] - s_fin[i0]);
    float inv = 1.0f / (1.0f + p1);
    float w0 = inv, w1 = p1 * inv;
    int s0 = atomicAdd(&counts[i0], 1);
    tokens[i0 * T_TOK + s0] = t; pairw[i0 * T_TOK + s0] = w0;
    int s1 = atomicAdd(&counts[i1], 1);
    tokens[i1 * T_TOK + s1] = t; pairw[i1 * T_TOK + s1] = w1;
  }
}

__global__ void k_scan(const int* __restrict__ counts, int* __restrict__ basep) {
  if (threadIdx.x == 0) {
    int s = 0;
    for (int e = 0; e < NEXP; e++) { basep[e] = s; s += counts[e]; }
  }
}

// ================= bf16-weight fast path =================

// ---------- Kernel B: gathered gate+up GEMM + silu -> h (bf16) ----------
__global__ __launch_bounds__(256, 2) void k_gateup_bf16(
    const ushort_t* __restrict__ xnorm, const ushort_t* __restrict__ wgb,
    const ushort_t* __restrict__ wub, const int* __restrict__ tokens,
    const int* __restrict__ counts, const int* __restrict__ basep,
    ushort_t* __restrict__ hbuf)
{
  const int e = blockIdx.z;
  const int cnt = counts[e];
  const int m0 = blockIdx.x * BM;
  if (m0 >= cnt) return;
  const int n0 = blockIdx.y * BN;
  const int tid = threadIdx.x;

  __shared__ ushort_t As[BM * BK];   // unpadded: required by global_load_lds layout
  __shared__ ushort_t Bg[BN * BK];
  __shared__ ushort_t Bu[BN * BK];

  const int lane = tid & 63;
  const int w = tid >> 6;
  // staging map: instr inst covers LDS bytes inst*1024 + lane*16
  // -> row = inst*8 + (lane>>3), col elements = (lane&7)*8
  const int srow = lane >> 3;
  const int scol = (lane & 7) * 8;

  const ushort_t* agp[4]; const ushort_t* ggp[4]; const ushort_t* ugp[4];
  #pragma unroll
  for (int i = 0; i < 4; i++) {
    const int rl = (w * 4 + i) * 8 + srow;
    const int slot = (m0 + rl < cnt) ? (m0 + rl) : (cnt - 1);
    const int tok = tokens[e * T_TOK + slot];
    agp[i] = xnorm + (size_t)tok * HDIM + scol;
    ggp[i] = wgb + ((size_t)e * IDIM + n0 + rl) * HDIM + scol;
    ugp[i] = wub + ((size_t)e * IDIM + n0 + rl) * HDIM + scol;
  }

  const int wm = (w & 1) * 64;
  const int wn = (w >> 1) * 64;
  const int fr = lane & 15;
  const int fq = lane >> 4;

  f32x4 accg[4][4] = {};
  f32x4 accu[4][4] = {};

  for (int k0 = 0; k0 < HDIM; k0 += BK) {
    #pragma unroll
    for (int i = 0; i < 4; i++) gll16(agp[i] + k0, &As[(w * 4 + i) * 512]);
    #pragma unroll
    for (int i = 0; i < 4; i++) gll16(ggp[i] + k0, &Bg[(w * 4 + i) * 512]);
    #pragma unroll
    for (int i = 0; i < 4; i++) gll16(ugp[i] + k0, &Bu[(w * 4 + i) * 512]);
    __syncthreads();
    #pragma unroll
    for (int kk = 0; kk < BK; kk += 32) {
      s16x8 af[4], bg[4], bu[4];
      #pragma unroll
      for (int mi = 0; mi < 4; mi++)
        af[mi] = *(const s16x8*)(&As[(wm + mi * 16 + fr) * BK + kk + fq * 8]);
      #pragma unroll
      for (int ni = 0; ni < 4; ni++) {
        bg[ni] = *(const s16x8*)(&Bg[(wn + ni * 16 + fr) * BK + kk + fq * 8]);
        bu[ni] = *(const s16x8*)(&Bu[(wn + ni * 16 + fr) * BK + kk + fq * 8]);
      }
      #pragma unroll
      for (int mi = 0; mi < 4; mi++) {
        #pragma unroll
        for (int ni = 0; ni < 4; ni++) {
          accg[mi][ni] = __builtin_amdgcn_mfma_f32_16x16x32_bf16(af[mi], bg[ni], accg[mi][ni], 0, 0, 0);
          accu[mi][ni] = __builtin_amdgcn_mfma_f32_16x16x32_bf16(af[mi], bu[ni], accu[mi][ni], 0, 0, 0);
        }
      }
    }
    __syncthreads();
  }

  const int hb = basep[e];
  #pragma unroll
  for (int mi = 0; mi < 4; mi++) {
    #pragma unroll
    for (int reg = 0; reg < 4; reg++) {
      const int rl = wm + mi * 16 + fq * 4 + reg;
      if (m0 + rl < cnt) {
        ushort_t* hrow = hbuf + (size_t)(hb + m0 + rl) * IDIM + n0;
        #pragma unroll
        for (int ni = 0; ni < 4; ni++) {
          float g = accg[mi][ni][reg];
          float u = accu[mi][ni][reg];
          float hv = (g / (1.0f + __expf(-g))) * u;
          hrow[wn + ni * 16 + fr] = f2bf(hv);
        }
      }
    }
  }
}

// ---------- Kernel C: down GEMM + weighted atomic combine ----------
__global__ __launch_bounds__(256, 3) void k_down_bf16(
    const ushort_t* __restrict__ hbuf, const ushort_t* __restrict__ wdb,
    const int* __restrict__ tokens, const float* __restrict__ pairw,
    const int* __restrict__ counts, const int* __restrict__ basep,
    float* __restrict__ out)
{
  const int e = blockIdx.z;
  const int cnt = counts[e];
  const int m0 = blockIdx.x * BM;
  if (m0 >= cnt) return;
  const int n0 = blockIdx.y * BN;
  const int tid = threadIdx.x;
  const int hb = basep[e];

  __shared__ ushort_t As[BM * BK];
  __shared__ ushort_t Bs[BN * BK];

  const int lane = tid & 63;
  const int w = tid >> 6;
  const int srow = lane >> 3;
  const int scol = (lane & 7) * 8;

  const ushort_t* agp[4]; const ushort_t* bgp[4];
  #pragma unroll
  for (int i = 0; i < 4; i++) {
    const int rl = (w * 4 + i) * 8 + srow;
    const int slot = (m0 + rl < cnt) ? (m0 + rl) : (cnt - 1);
    agp[i] = hbuf + (size_t)(hb + slot) * IDIM + scol;
    bgp[i] = wdb + ((size_t)e * HDIM + n0 + rl) * IDIM + scol;
  }

  const int wm = (w & 1) * 64;
  const int wn = (w >> 1) * 64;
  const int fr = lane & 15;
  const int fq = lane >> 4;

  f32x4 acc[4][4] = {};

  for (int k0 = 0; k0 < IDIM; k0 += BK) {
    #pragma unroll
    for (int i = 0; i < 4; i++) gll16(agp[i] + k0, &As[(w * 4 + i) * 512]);
    #pragma unroll
    for (int i = 0; i < 4; i++) gll16(bgp[i] + k0, &Bs[(w * 4 + i) * 512]);
    __syncthreads();
    #pragma unroll
    for (int kk = 0; kk < BK; kk += 32) {
      s16x8 af[4], bf[4];
      #pragma unroll
      for (int mi = 0; mi < 4; mi++)
        af[mi] = *(const s16x8*)(&As[(wm + mi * 16 + fr) * BK + kk + fq * 8]);
      #pragma unroll
      for (int ni = 0; ni < 4; ni++)
        bf[ni] = *(const s16x8*)(&Bs[(wn + ni * 16 + fr) * BK + kk + fq * 8]);
      #pragma unroll
      for (int mi = 0; mi < 4; mi++) {
        #pragma unroll
        for (int ni = 0; ni < 4; ni++)
          acc[mi][ni] = __builtin_amdgcn_mfma_f32_16x16x32_bf16(af[mi], bf[ni], acc[mi][ni], 0, 0, 0);
      }
    }
    __syncthreads();
  }

  #pragma unroll
  for (int mi = 0; mi < 4; mi++) {
    #pragma unroll
    for (int reg = 0; reg < 4; reg++) {
      const int rl = wm + mi * 16 + fq * 4 + reg;
      if (m0 + rl < cnt) {
        const int tok = tokens[e * T_TOK + m0 + rl];
        const float ww = pairw[e * T_TOK + m0 + rl];
        float* orow = out + (size_t)tok * HDIM + n0;
        #pragma unroll
        for (int ni = 0; ni < 4; ni++)
          atomicAdd(&orow[wn + ni * 16 + fr], ww * acc[mi][ni][reg]);
      }
    }
  }
}

// ================= fp32-weight fallback path (round-1 kernels) =================

__global__ __launch_bounds__(256, 2) void k_gateup_f32(
    const ushort_t* __restrict__ xnorm, const float* __restrict__ wg,
    const float* __restrict__ wu, const int* __restrict__ tokens,
    const int* __restrict__ counts, const int* __restrict__ basep,
    ushort_t* __restrict__ hbuf)
{
  const int e = blockIdx.z;
  const int cnt = counts[e];
  const int m0 = blockIdx.x * BM;
  if (m0 >= cnt) return;
  const int n0 = blockIdx.y * BN;
  const int tid = threadIdx.x;

  __shared__ ushort_t As[BM * LDK];
  __shared__ ushort_t Bgs[BN * LDK];
  __shared__ ushort_t Bus[BN * LDK];

  const int r = tid >> 1;
  const int col0 = (tid & 1) * 32;
  const int slot = (m0 + r < cnt) ? (m0 + r) : (cnt - 1);
  const int tok = tokens[e * T_TOK + slot];
  const ushort_t* asrc = xnorm + (size_t)tok * HDIM + col0;
  const float* gsrc = wg + ((size_t)e * IDIM + n0 + r) * HDIM + col0;
  const float* usrc = wu + ((size_t)e * IDIM + n0 + r) * HDIM + col0;

  const int lane = tid & 63;
  const int wid = tid >> 6;
  const int wm = (wid & 1) * 64;
  const int wn = (wid >> 1) * 64;
  const int fr = lane & 15;
  const int fq = lane >> 4;

  f32x4 accg[4][4] = {};
  f32x4 accu[4][4] = {};

  for (int k0 = 0; k0 < HDIM; k0 += BK) {
    #pragma unroll
    for (int i = 0; i < 4; i++) {
      uint4 v = *(const uint4*)(asrc + k0 + i * 8);
      *(uint4*)(&As[r * LDK + col0 + i * 8]) = v;
    }
    #pragma unroll
    for (int i = 0; i < 4; i++) {
      float4 f0 = *(const float4*)(gsrc + k0 + i * 8);
      float4 f1 = *(const float4*)(gsrc + k0 + i * 8 + 4);
      union { ushort_t us[8]; uint4 v; } p;
      p.us[0]=f2bf(f0.x); p.us[1]=f2bf(f0.y); p.us[2]=f2bf(f0.z); p.us[3]=f2bf(f0.w);
      p.us[4]=f2bf(f1.x); p.us[5]=f2bf(f1.y); p.us[6]=f2bf(f1.z); p.us[7]=f2bf(f1.w);
      *(uint4*)(&Bgs[r * LDK + col0 + i * 8]) = p.v;
    }
    #pragma unroll
    for (int i = 0; i < 4; i++) {
      float4 f0 = *(const float4*)(usrc + k0 + i * 8);
      float4 f1 = *(const float4*)(usrc + k0 + i * 8 + 4);
      union { ushort_t us[8]; uint4 v; } p;
      p.us[0]=f2bf(f0.x); p.us[1]=f2bf(f0.y); p.us[2]=f2bf(f0.z); p.us[3]=f2bf(f0.w);
      p.us[4]=f2bf(f1.x); p.us[5]=f2bf(f1.y); p.us[6]=f2bf(f1.z); p.us[7]=f2bf(f1.w);
      *(uint4*)(&Bus[r * LDK + col0 + i * 8]) = p.v;
    }
    __syncthreads();
    #pragma unroll
    for (int kk = 0; kk < BK; kk += 32) {
      s16x8 af[4], bg[4], bu[4];
      #pragma unroll
      for (int mi = 0; mi < 4; mi++)
        af[mi] = *(const s16x8*)(&As[(wm + mi * 16 + fr) * LDK + kk + fq * 8]);
      #pragma unroll
      for (int ni = 0; ni < 4; ni++) {
        bg[ni] = *(const s16x8*)(&Bgs[(wn + ni * 16 + fr) * LDK + kk + fq * 8]);
        bu[ni] = *(const s16x8*)(&Bus[(wn + ni * 16 + fr) * LDK + kk + fq * 8]);
      }
      #pragma unroll
      for (int mi = 0; mi < 4; mi++) {
        #pragma unroll
        for (int ni = 0; ni < 4; ni++) {
          accg[mi][ni] = __builtin_amdgcn_mfma_f32_16x16x32_bf16(af[mi], bg[ni], accg[mi][ni], 0, 0, 0);
          accu[mi][ni] = __builtin_amdgcn_mfma_f32_16x16x32_bf16(af[mi], bu[ni], accu[mi][ni], 0, 0, 0);
        }
      }
    }
    __syncthreads();
  }

  const int hb = basep[e];
  #pragma unroll
  for (int mi = 0; mi < 4; mi++) {
    #pragma unroll
    for (int reg = 0; reg < 4; reg++) {
      const int rl = wm + mi * 16 + fq * 4 + reg;
      if (m0 + rl < cnt) {
        ushort_t* hrow = hbuf + (size_t)(hb + m0 + rl) * IDIM + n0;
        #pragma unroll
        for (int ni = 0; ni < 4; ni++) {
          float g = accg[mi][ni][reg];
          float u = accu[mi][ni][reg];
          float hv = (g / (1.0f + __expf(-g))) * u;
          hrow[wn + ni * 16 + fr] = f2bf(hv);
        }
      }
    }
  }
}

__global__ __launch_bounds__(256, 2) void k_down_f32(
    const ushort_t* __restrict__ hbuf, const float* __restrict__ wd,
    const int* __restrict__ tokens, const float* __restrict__ pairw,
    const int* __restrict__ counts, const int* __restrict__ basep,
    float* __restrict__ out)
{
  const int e = blockIdx.z;
  const int cnt = counts[e];
  const int m0 = blockIdx.x * BM;
  if (m0 >= cnt) return;
  const int n0 = blockIdx.y * BN;
  const int tid = threadIdx.x;
  const int hb = basep[e];

  __shared__ ushort_t As[BM * LDK];
  __shared__ ushort_t Bs[BN * LDK];

  const int r = tid >> 1;
  const int col0 = (tid & 1) * 32;
  const int slot = (m0 + r < cnt) ? (m0 + r) : (cnt - 1);
  const ushort_t* asrc = hbuf + (size_t)(hb + slot) * IDIM + col0;
  const float* bsrc = wd + ((size_t)e * HDIM + n0 + r) * IDIM + col0;

  const int lane = tid & 63;
  const int wid = tid >> 6;
  const int wm = (wid & 1) * 64;
  const int wn = (wid >> 1) * 64;
  const int fr = lane & 15;
  const int fq = lane >> 4;

  f32x4 acc[4][4] = {};

  for (int k0 = 0; k0 < IDIM; k0 += BK) {
    #pragma unroll
    for (int i = 0; i < 4; i++) {
      uint4 v = *(const uint4*)(asrc + k0 + i * 8);
      *(uint4*)(&As[r * LDK + col0 + i * 8]) = v;
    }
    #pragma unroll
    for (int i = 0; i < 4; i++) {
      float4 f0 = *(const float4*)(bsrc + k0 + i * 8);
      float4 f1 = *(const float4*)(bsrc + k0 + i * 8 + 4);
      union { ushort_t us[8]; uint4 v; } p;
      p.us[0]=f2bf(f0.x); p.us[1]=f2bf(f0.y); p.us[2]=f2bf(f0.z); p.us[3]=f2bf(f0.w);
      p.us[4]=f2bf(f1.x); p.us[5]=f2bf(f1.y); p.us[6]=f2bf(f1.z); p.us[7]=f2bf(f1.w);
      *(uint4*)(&Bs[r * LDK + col0 + i * 8]) = p.v;
    }
    __syncthreads();
    #pragma unroll
    for (int kk = 0; kk < BK; kk += 32) {
      s16x8 af[4], bf[4];
      #pragma unroll
      for (int mi = 0; mi < 4; mi++)
        af[mi] = *(const s16x8*)(&As[(wm + mi * 16 + fr) * LDK + kk + fq * 8]);
      #pragma unroll
      for (int ni = 0; ni < 4; ni++)
        bf[ni] = *(const s16x8*)(&Bs[(wn + ni * 16 + fr) * LDK + kk + fq * 8]);
      #pragma unroll
      for (int mi = 0; mi < 4; mi++) {
        #pragma unroll
        for (int ni = 0; ni < 4; ni++)
          acc[mi][ni] = __builtin_amdgcn_mfma_f32_16x16x32_bf16(af[mi], bf[ni], acc[mi][ni], 0, 0, 0);
      }
    }
    __syncthreads();
  }

  #pragma unroll
  for (int mi = 0; mi < 4; mi++) {
    #pragma unroll
    for (int reg = 0; reg < 4; reg++) {
      const int rl = wm + mi * 16 + fq * 4 + reg;
      if (m0 + rl < cnt) {
        const int tok = tokens[e * T_TOK + m0 + rl];
        const float ww = pairw[e * T_TOK + m0 + rl];
        float* orow = out + (size_t)tok * HDIM + n0;
        #pragma unroll
        for (int ni = 0; ni < 4; ni++)
          atomicAdd(&orow[wn + ni * 16 + fr], ww * acc[mi][ni][reg]);
      }
    }
  }
}

extern "C" void kernel_launch(void* const* d_in, const int* in_sizes, int n_in,
                              void* d_out, int out_size, void* d_ws, size_t ws_size,
                              hipStream_t stream)
{
  (void)in_sizes; (void)n_in;
  const float* x    = (const float*)d_in[0];
  const float* rmsw = (const float*)d_in[1];
  const float* rw   = (const float*)d_in[2];
  const float* wg   = (const float*)d_in[3];
  const float* wu   = (const float*)d_in[4];
  const float* wd   = (const float*)d_in[5];
  float* out = (float*)d_out;
  float* logits_out = out + (size_t)T_TOK * HDIM;

  const size_t WB = (size_t)NEXP * IDIM * HDIM * 2;   // 46,137,344 B per bf16 weight
  const size_t HB = (size_t)2 * T_TOK * IDIM * 2;     // 46,137,344 B hbuf
  const size_t XB = (size_t)T_TOK * HDIM * 2;         // 33,554,432 B xnorm
  const size_t BOOK = 1024 + 2 * (size_t)NEXP * T_TOK * 4;  // counts/basep/tokens/pairw

  char* ws = (char*)d_ws;
  int* counts  = (int*)ws;
  int* basep   = (int*)(ws + 256);
  int* tokens  = (int*)(ws + 1024);
  float* pairw = (float*)(ws + 1024 + (size_t)NEXP * T_TOK * 4);

  hipMemsetAsync(d_out, 0, (size_t)out_size * sizeof(float), stream);
  hipMemsetAsync(d_ws, 0, 512, stream);

  const size_t NEED = BOOK + HB + 2 * WB + ((WB > XB) ? WB : XB) + 4096;
  const int n8 = (int)((size_t)NEXP * IDIM * HDIM / 8);  // elems/8 per weight tensor

  if (ws_size >= NEED) {
    // fast path: bf16 weights + global_load_lds
    ushort_t* hbuf  = (ushort_t*)(ws + BOOK);
    ushort_t* wgb   = (ushort_t*)(ws + BOOK + HB);
    ushort_t* wub   = (ushort_t*)(ws + BOOK + HB + WB);
    ushort_t* xnorm = (ushort_t*)(ws + BOOK + HB + 2 * WB);
    ushort_t* wdb   = (ushort_t*)(ws + BOOK + HB + 2 * WB);  // aliases xnorm (used after)

    k_cast<<<(n8 + 255) / 256, 256, 0, stream>>>(wg, wgb, n8);
    k_cast<<<(n8 + 255) / 256, 256, 0, stream>>>(wu, wub, n8);
    k_rms_router<<<T_TOK, 256, 0, stream>>>(x, rmsw, rw, xnorm, logits_out,
                                            counts, tokens, pairw);
    k_scan<<<1, 64, 0, stream>>>(counts, basep);
    k_gateup_bf16<<<dim3(T_TOK / BM, IDIM / BN, NEXP), 256, 0, stream>>>(
        xnorm, wgb, wub, tokens, counts, basep, hbuf);
    k_cast<<<(n8 + 255) / 256, 256, 0, stream>>>(wd, wdb, n8);  // overwrites xnorm (done)
    k_down_bf16<<<dim3(T_TOK / BM, HDIM / BN, NEXP), 256, 0, stream>>>(
        hbuf, wdb, tokens, pairw, counts, basep, out);
  } else {
    // fallback: round-1 fp32-staging path (~80 MB ws)
    ushort_t* xnorm = (ushort_t*)(ws + BOOK);
    ushort_t* hbuf  = (ushort_t*)(ws + BOOK + XB);

    k_rms_router<<<T_TOK, 256, 0, stream>>>(x, rmsw, rw, xnorm, logits_out,
                                            counts, tokens, pairw);
    k_scan<<<1, 64, 0, stream>>>(counts, basep);
    k_gateup_f32<<<dim3(T_TOK / BM, IDIM / BN, NEXP), 256, 0, stream>>>(
        xnorm, wg, wu, tokens, counts, basep, hbuf);
    k_down_f32<<<dim3(T_TOK / BM, HDIM / BN, NEXP), 256, 0, stream>>>(
        hbuf, wd, tokens, pairw, counts, basep, out);
  }
}